// Round 1
// baseline (1469.622 us; speedup 1.0000x reference)
//
#include <hip/hip_runtime.h>

// DeepAR forward: B=32, L_IN=336, L_OUT=48, N=512, COV=4, EMB=32, H=64
// T = 383 steps, BN = 16384 independent sequences.
// Strategy: 32 sequences per 256-thread WG (512 WGs), persistent loop over T.
// Gate matmuls via mfma_f32_16x16x32_bf16; weights as B-fragments in VGPRs;
// input projection folded into K (layer0 K=96), biases folded into acc init.
// c-state fp32 in registers; h-state bf16 via LDS (padded strides 104/136).

#define T_STEPS 383

typedef __attribute__((ext_vector_type(8))) short short8;
typedef __attribute__((ext_vector_type(4))) float floatx4;

__device__ __forceinline__ unsigned short f2bf(float f){
  union { float f; unsigned u; } v; v.f = f;
  unsigned u = v.u + 0x7fffu + ((v.u >> 16) & 1u);
  return (unsigned short)(u >> 16);
}
__device__ __forceinline__ float bf2f(unsigned short b){
  union { unsigned u; float f; } v; v.u = ((unsigned)b) << 16; return v.f;
}
__device__ __forceinline__ float fsig(float x){
  return __builtin_amdgcn_rcpf(1.f + __expf(-x));
}
__device__ __forceinline__ float ftanh(float x){
  // tanh(x) = 1 - 2/(1+e^{2x}); stable at both infinities
  return 1.f - 2.f * __builtin_amdgcn_rcpf(1.f + __expf(2.f * x));
}

__global__ __launch_bounds__(256, 2) void deepar_kernel(
    const float* __restrict__ hist, const float* __restrict__ fut,
    const float* __restrict__ embW, const float* __restrict__ embB,
    const float* __restrict__ Wih0, const float* __restrict__ Whh0,
    const float* __restrict__ bih0, const float* __restrict__ bhh0,
    const float* __restrict__ Wih1, const float* __restrict__ Whh1,
    const float* __restrict__ bih1, const float* __restrict__ bhh1,
    const float* __restrict__ headW, const float* __restrict__ headB,
    float* __restrict__ outp)
{
  const int tid  = threadIdx.x;
  const int lane = tid & 63;
  const int wv   = tid >> 6;        // wave 0..3 -> gate-row sub-block j in [wv*16, wv*16+16)
  const int l15  = lane & 15;
  const int quad = lane >> 4;       // 0..3
  const int koff = quad * 8;
  const int jcol = wv * 16 + l15;   // hidden-unit index this lane owns

  const int b  = blockIdx.x >> 4;            // batch
  const int n0 = (blockIdx.x & 15) * 32;     // first series index

  // A0: layer0 MFMA A-matrix [32 seq][96 k] pad->104 (k 0..63 = h0, 64=prev, 65..68=cov, 69..95=0)
  // A1: layer1 MFMA A-matrix [32 seq][128 k] pad->136 (0..63 = h0_new, 64..127 = h1)
  __shared__ __align__(16) unsigned short A0[32 * 104];
  __shared__ __align__(16) unsigned short A1[32 * 136];
  __shared__ float HW[128];

  for (int i = tid; i < 32 * 104; i += 256) A0[i] = 0;
  for (int i = tid; i < 32 * 136; i += 256) A1[i] = 0;
  if (tid < 128) HW[tid] = headW[tid];
  const float hb0 = headB[0], hb1 = headB[1];

  // ---- build weight B-fragments in registers ----
  // B-frag layout (16x16x32): lane holds B^T[n=lane&15][k = quad*8 + j], j=0..7
  short8 bf0[4][3];   // layer0: gates x K-frags (K=96)
  short8 bf1[4][4];   // layer1: gates x K-frags (K=128: Wih1 | Whh1)
  float  bi0[4], bi1[4];
  #pragma unroll
  for (int g = 0; g < 4; ++g){
    const int r = g * 64 + wv * 16 + l15;     // gate row 0..255
    float u = 0.f, bb = bih0[r] + bhh0[r];
    #pragma unroll
    for (int e = 0; e < 32; ++e){
      float wval = Wih0[r * 36 + e];
      u  += wval * embW[e];
      bb += wval * embB[e];
    }
    bi0[g] = bb;
    bi1[g] = bih1[r] + bhh1[r];
    #pragma unroll
    for (int kf = 0; kf < 2; ++kf)
      #pragma unroll
      for (int j = 0; j < 8; ++j)
        bf0[g][kf][j] = (short)f2bf(Whh0[r * 64 + kf * 32 + koff + j]);
    #pragma unroll
    for (int j = 0; j < 8; ++j){
      int k = 64 + koff + j;
      float v = 0.f;
      if (k == 64) v = u;                          // prev -> u[r]
      else if (k >= 65 && k <= 68) v = Wih0[r * 36 + 32 + (k - 65)];  // cov weights
      bf0[g][2][j] = (short)f2bf(v);
    }
    #pragma unroll
    for (int kf = 0; kf < 4; ++kf){
      const float* src = (kf < 2) ? (Wih1 + r * 64 + kf * 32)
                                  : (Whh1 + r * 64 + (kf - 2) * 32);
      #pragma unroll
      for (int j = 0; j < 8; ++j)
        bf1[g][kf][j] = (short)f2bf(src[koff + j]);
    }
  }

  // ---- input staging assignment (prev: 32 threads; cov: 128 threads) ----
  const bool isPrev = (tid < 32);
  const bool isCov  = (tid >= 64 && tid < 192);
  int ss = 0, cc = 0;
  if (isPrev){ ss = tid; cc = 0; }
  if (isCov) { ss = (tid - 64) >> 2; cc = 1 + ((tid - 64) & 3); }
  const int myN = n0 + ss;

  auto loadSlab = [&](int tt) -> float {
    if (isPrev){
      int l = tt; if (l > 383) l = 383;
      return (l < 336) ? hist[(((size_t)b * 336 + l) * 512 + myN) * 5]
                       : fut [(((size_t)b * 48 + (l - 336)) * 512 + myN) * 5];
    } else if (isCov){
      int l = tt + 1; if (l > 383) l = 383;
      return (l < 336) ? hist[(((size_t)b * 336 + l) * 512 + myN) * 5 + cc]
                       : fut [(((size_t)b * 48 + (l - 336)) * 512 + myN) * 5 + cc];
    }
    return 0.f;
  };

  float rIn = loadSlab(0);
  if (isPrev || isCov) A0[ss * 104 + 64 + cc] = f2bf(rIn);
  rIn = loadSlab(1);   // prefetch step 1

  float c0s[8], c1s[8];
  #pragma unroll
  for (int i = 0; i < 8; ++i){ c0s[i] = 0.f; c1s[i] = 0.f; }

  __syncthreads();

  for (int t = 0; t < T_STEPS; ++t){
    // ================= layer 0 =================
    floatx4 acc[4][2];
    #pragma unroll
    for (int g = 0; g < 4; ++g)
      #pragma unroll
      for (int mt = 0; mt < 2; ++mt){
        floatx4 binit = { bi0[g], bi0[g], bi0[g], bi0[g] };
        acc[g][mt] = binit;
      }
    #pragma unroll
    for (int mt = 0; mt < 2; ++mt){
      #pragma unroll
      for (int kf = 0; kf < 3; ++kf){
        short8 af = *(const short8*)&A0[(mt * 16 + l15) * 104 + kf * 32 + koff];
        #pragma unroll
        for (int g = 0; g < 4; ++g)
          acc[g][mt] = __builtin_amdgcn_mfma_f32_16x16x32_bf16(af, bf0[g][kf], acc[g][mt], 0, 0, 0);
      }
    }
    float hn[8];
    #pragma unroll
    for (int mt = 0; mt < 2; ++mt)
      #pragma unroll
      for (int q = 0; q < 4; ++q){
        int idx = mt * 4 + q;
        float iv = acc[0][mt][q], fv = acc[1][mt][q];
        float gv = acc[2][mt][q], ov = acc[3][mt][q];
        float c = fsig(fv) * c0s[idx] + fsig(iv) * ftanh(gv);
        c0s[idx] = c;
        hn[idx] = fsig(ov) * ftanh(c);
      }
    __syncthreads();   // all layer-0 reads of A0 done
    #pragma unroll
    for (int mt = 0; mt < 2; ++mt)
      #pragma unroll
      for (int q = 0; q < 4; ++q){
        int s = mt * 16 + quad * 4 + q;
        unsigned short hb = f2bf(hn[mt * 4 + q]);
        A0[s * 104 + jcol] = hb;   // h0 for next step's layer 0
        A1[s * 136 + jcol] = hb;   // h0 for this step's layer 1
      }
    if (isPrev || isCov) A0[ss * 104 + 64 + cc] = f2bf(rIn);   // inputs for step t+1
    rIn = loadSlab(t + 2);                                     // prefetch step t+2
    __syncthreads();   // h0 + inputs visible

    // ================= layer 1 =================
    #pragma unroll
    for (int g = 0; g < 4; ++g)
      #pragma unroll
      for (int mt = 0; mt < 2; ++mt){
        floatx4 binit = { bi1[g], bi1[g], bi1[g], bi1[g] };
        acc[g][mt] = binit;
      }
    #pragma unroll
    for (int mt = 0; mt < 2; ++mt){
      #pragma unroll
      for (int kf = 0; kf < 4; ++kf){
        short8 af = *(const short8*)&A1[(mt * 16 + l15) * 136 + kf * 32 + koff];
        #pragma unroll
        for (int g = 0; g < 4; ++g)
          acc[g][mt] = __builtin_amdgcn_mfma_f32_16x16x32_bf16(af, bf1[g][kf], acc[g][mt], 0, 0, 0);
      }
    }
    #pragma unroll
    for (int mt = 0; mt < 2; ++mt)
      #pragma unroll
      for (int q = 0; q < 4; ++q){
        int idx = mt * 4 + q;
        float iv = acc[0][mt][q], fv = acc[1][mt][q];
        float gv = acc[2][mt][q], ov = acc[3][mt][q];
        float c = fsig(fv) * c1s[idx] + fsig(iv) * ftanh(gv);
        c1s[idx] = c;
        hn[idx] = fsig(ov) * ftanh(c);
      }
    __syncthreads();   // all layer-1 reads of h1_prev done
    #pragma unroll
    for (int mt = 0; mt < 2; ++mt)
      #pragma unroll
      for (int q = 0; q < 4; ++q){
        int s = mt * 16 + quad * 4 + q;
        A1[s * 136 + 64 + jcol] = f2bf(hn[mt * 4 + q]);
      }
    __syncthreads();   // h1 visible

    // ================= head =================
    {
      const int hs = tid >> 3, outc = (tid >> 2) & 1, part = tid & 3;
      float p = 0.f;
      #pragma unroll
      for (int jj = 0; jj < 16; ++jj){
        int j = part * 16 + jj;
        float hv = bf2f(A1[hs * 136 + 64 + j]);
        hv = fmaxf(hv, 0.f);
        p += hv * HW[outc * 64 + j];
      }
      p += __shfl_xor(p, 1);
      p += __shfl_xor(p, 2);
      if (((tid & 3) == 0) && t >= 335){
        float val;
        if (outc == 0) val = p + hb0;
        else {
          float x = p + hb1;   // softplus, stable
          val = fmaxf(x, 0.f) + __logf(1.f + __expf(-fabsf(x)));
        }
        outp[(((size_t)b * 48 + (t - 335)) * 512 + (n0 + hs)) * 2 + outc] = val;
      }
    }
  }
}

extern "C" void kernel_launch(void* const* d_in, const int* in_sizes, int n_in,
                              void* d_out, int out_size, void* d_ws, size_t ws_size,
                              hipStream_t stream) {
  (void)in_sizes; (void)n_in; (void)out_size; (void)d_ws; (void)ws_size;
  deepar_kernel<<<dim3(512), dim3(256), 0, stream>>>(
      (const float*)d_in[0],  (const float*)d_in[1],
      (const float*)d_in[2],  (const float*)d_in[3],
      (const float*)d_in[4],  (const float*)d_in[5],
      (const float*)d_in[6],  (const float*)d_in[7],
      (const float*)d_in[8],  (const float*)d_in[9],
      (const float*)d_in[10], (const float*)d_in[11],
      (const float*)d_in[12], (const float*)d_in[13],
      (float*)d_out);
}

// Round 2
// 1388.930 us; speedup vs baseline: 1.0581x; 1.0581x over previous
//
#include <hip/hip_runtime.h>

// DeepAR forward: B=32, L_IN=336, L_OUT=48, N=512, COV=4, EMB=32, H=64
// T = 383 steps, BN = 16384 independent sequences.
// 32 sequences per 256-thread WG (512 WGs = 2 blocks/CU), persistent over T.
// Gate matmuls via mfma_f32_16x16x32_bf16; weights as B-fragments in VGPRs
// (112 VGPRs/wave -> needs waves_per_eu(2,2) for the 256-VGPR budget, else
// the compiler targets 4 waves/EU @128 VGPRs and spills weights to scratch:
// R1 showed WRITE_SIZE=103MB of scratch leakage at VGPR_Count=128).
// Input projection folded into K (layer0 K=96), biases folded into acc init.
// c-state fp32 in registers; h-state bf16 via LDS (padded strides 104/136).
// Head computed only for t>=335 (only last 48 steps are output).

#define T_STEPS 383

typedef __attribute__((ext_vector_type(8))) short short8;
typedef __attribute__((ext_vector_type(4))) float floatx4;

__device__ __forceinline__ unsigned short f2bf(float f){
  union { float f; unsigned u; } v; v.f = f;
  unsigned u = v.u + 0x7fffu + ((v.u >> 16) & 1u);
  return (unsigned short)(u >> 16);
}
__device__ __forceinline__ float bf2f(unsigned short b){
  union { unsigned u; float f; } v; v.u = ((unsigned)b) << 16; return v.f;
}
__device__ __forceinline__ float fsig(float x){
  return __builtin_amdgcn_rcpf(1.f + __expf(-x));
}
__device__ __forceinline__ float ftanh(float x){
  // tanh(x) = 1 - 2/(1+e^{2x}); stable at both infinities
  return 1.f - 2.f * __builtin_amdgcn_rcpf(1.f + __expf(2.f * x));
}

__global__ void
__attribute__((amdgpu_flat_work_group_size(256, 256), amdgpu_waves_per_eu(2, 2)))
deepar_kernel(
    const float* __restrict__ hist, const float* __restrict__ fut,
    const float* __restrict__ embW, const float* __restrict__ embB,
    const float* __restrict__ Wih0, const float* __restrict__ Whh0,
    const float* __restrict__ bih0, const float* __restrict__ bhh0,
    const float* __restrict__ Wih1, const float* __restrict__ Whh1,
    const float* __restrict__ bih1, const float* __restrict__ bhh1,
    const float* __restrict__ headW, const float* __restrict__ headB,
    float* __restrict__ outp)
{
  const int tid  = threadIdx.x;
  const int lane = tid & 63;
  const int wv   = tid >> 6;        // wave 0..3 -> gate-row sub-block
  const int l15  = lane & 15;
  const int quad = lane >> 4;       // 0..3
  const int koff = quad * 8;
  const int jcol = wv * 16 + l15;   // hidden-unit index this lane owns

  const int b  = blockIdx.x >> 4;            // batch
  const int n0 = (blockIdx.x & 15) * 32;     // first series index

  // A0: layer0 MFMA A [32 seq][96 k] pad->104 (k 0..63 = h0, 64=prev, 65..68=cov, 69..95=0)
  // A1: layer1 MFMA A [32 seq][128 k] pad->136 (0..63 = h0_new, 64..127 = h1)
  __shared__ __align__(16) unsigned short A0[32 * 104];
  __shared__ __align__(16) unsigned short A1[32 * 136];
  __shared__ float HW[128];

  for (int i = tid; i < 32 * 104; i += 256) A0[i] = 0;
  for (int i = tid; i < 32 * 136; i += 256) A1[i] = 0;
  if (tid < 128) HW[tid] = headW[tid];
  const float hb0 = headB[0], hb1 = headB[1];

  // ---- build weight B-fragments in registers ----
  // B-frag layout (16x16x32): lane holds B^T[n=lane&15][k = quad*8 + j]
  short8 bf0[4][3];   // layer0: gates x K-frags (K=96)
  short8 bf1[4][4];   // layer1: gates x K-frags (K=128: Wih1 | Whh1)
  float  bi0[4], bi1[4];
  #pragma unroll
  for (int g = 0; g < 4; ++g){
    const int r = g * 64 + wv * 16 + l15;     // gate row 0..255
    float u = 0.f, bb = bih0[r] + bhh0[r];
    #pragma unroll
    for (int e = 0; e < 32; ++e){
      float wval = Wih0[r * 36 + e];
      u  += wval * embW[e];
      bb += wval * embB[e];
    }
    bi0[g] = bb;
    bi1[g] = bih1[r] + bhh1[r];
    #pragma unroll
    for (int kf = 0; kf < 2; ++kf)
      #pragma unroll
      for (int j = 0; j < 8; ++j)
        bf0[g][kf][j] = (short)f2bf(Whh0[r * 64 + kf * 32 + koff + j]);
    #pragma unroll
    for (int j = 0; j < 8; ++j){
      int k = 64 + koff + j;
      float v = 0.f;
      if (k == 64) v = u;                          // prev -> u[r]
      else if (k >= 65 && k <= 68) v = Wih0[r * 36 + 32 + (k - 65)];
      bf0[g][2][j] = (short)f2bf(v);
    }
    #pragma unroll
    for (int kf = 0; kf < 4; ++kf){
      const float* src = (kf < 2) ? (Wih1 + r * 64 + kf * 32)
                                  : (Whh1 + r * 64 + (kf - 2) * 32);
      #pragma unroll
      for (int j = 0; j < 8; ++j)
        bf1[g][kf][j] = (short)f2bf(src[koff + j]);
    }
  }

  // ---- input staging (prev: 32 threads; cov: 128 threads) ----
  const bool isPrev = (tid < 32);
  const bool isCov  = (tid >= 64 && tid < 192);
  int ss = 0, cc = 0;
  if (isPrev){ ss = tid; cc = 0; }
  if (isCov) { ss = (tid - 64) >> 2; cc = 1 + ((tid - 64) & 3); }
  const int myN = n0 + ss;

  auto loadSlab = [&](int tt) -> float {
    if (isPrev){
      int l = tt; if (l > 383) l = 383;
      return (l < 336) ? hist[(((size_t)b * 336 + l) * 512 + myN) * 5]
                       : fut [(((size_t)b * 48 + (l - 336)) * 512 + myN) * 5];
    } else if (isCov){
      int l = tt + 1; if (l > 383) l = 383;
      return (l < 336) ? hist[(((size_t)b * 336 + l) * 512 + myN) * 5 + cc]
                       : fut [(((size_t)b * 48 + (l - 336)) * 512 + myN) * 5 + cc];
    }
    return 0.f;
  };

  float rIn = loadSlab(0);
  if (isPrev || isCov) A0[ss * 104 + 64 + cc] = f2bf(rIn);
  rIn = loadSlab(1);   // prefetch step 1

  float c0s[8], c1s[8];
  #pragma unroll
  for (int i = 0; i < 8; ++i){ c0s[i] = 0.f; c1s[i] = 0.f; }

  __syncthreads();

  for (int t = 0; t < T_STEPS; ++t){
    // ================= layer 0 =================
    floatx4 acc[4][2];
    #pragma unroll
    for (int g = 0; g < 4; ++g)
      #pragma unroll
      for (int mt = 0; mt < 2; ++mt){
        floatx4 binit = { bi0[g], bi0[g], bi0[g], bi0[g] };
        acc[g][mt] = binit;
      }
    #pragma unroll
    for (int mt = 0; mt < 2; ++mt){
      #pragma unroll
      for (int kf = 0; kf < 3; ++kf){
        short8 af = *(const short8*)&A0[(mt * 16 + l15) * 104 + kf * 32 + koff];
        #pragma unroll
        for (int g = 0; g < 4; ++g)
          acc[g][mt] = __builtin_amdgcn_mfma_f32_16x16x32_bf16(af, bf0[g][kf], acc[g][mt], 0, 0, 0);
      }
    }
    float hn[8];
    #pragma unroll
    for (int mt = 0; mt < 2; ++mt)
      #pragma unroll
      for (int q = 0; q < 4; ++q){
        int idx = mt * 4 + q;
        float iv = acc[0][mt][q], fv = acc[1][mt][q];
        float gv = acc[2][mt][q], ov = acc[3][mt][q];
        float c = fsig(fv) * c0s[idx] + fsig(iv) * ftanh(gv);
        c0s[idx] = c;
        hn[idx] = fsig(ov) * ftanh(c);
      }
    __syncthreads();   // all layer-0 reads of A0 done
    #pragma unroll
    for (int mt = 0; mt < 2; ++mt)
      #pragma unroll
      for (int q = 0; q < 4; ++q){
        int s = mt * 16 + quad * 4 + q;
        unsigned short hb = f2bf(hn[mt * 4 + q]);
        A0[s * 104 + jcol] = hb;   // h0 for next step's layer 0
        A1[s * 136 + jcol] = hb;   // h0 for this step's layer 1
      }
    if (isPrev || isCov) A0[ss * 104 + 64 + cc] = f2bf(rIn);   // inputs for t+1
    rIn = loadSlab(t + 2);                                     // prefetch t+2
    __syncthreads();   // h0 + inputs visible

    // ================= layer 1 =================
    #pragma unroll
    for (int g = 0; g < 4; ++g)
      #pragma unroll
      for (int mt = 0; mt < 2; ++mt){
        floatx4 binit = { bi1[g], bi1[g], bi1[g], bi1[g] };
        acc[g][mt] = binit;
      }
    #pragma unroll
    for (int mt = 0; mt < 2; ++mt){
      #pragma unroll
      for (int kf = 0; kf < 4; ++kf){
        short8 af = *(const short8*)&A1[(mt * 16 + l15) * 136 + kf * 32 + koff];
        #pragma unroll
        for (int g = 0; g < 4; ++g)
          acc[g][mt] = __builtin_amdgcn_mfma_f32_16x16x32_bf16(af, bf1[g][kf], acc[g][mt], 0, 0, 0);
      }
    }
    #pragma unroll
    for (int mt = 0; mt < 2; ++mt)
      #pragma unroll
      for (int q = 0; q < 4; ++q){
        int idx = mt * 4 + q;
        float iv = acc[0][mt][q], fv = acc[1][mt][q];
        float gv = acc[2][mt][q], ov = acc[3][mt][q];
        float c = fsig(fv) * c1s[idx] + fsig(iv) * ftanh(gv);
        c1s[idx] = c;
        hn[idx] = fsig(ov) * ftanh(c);
      }
    __syncthreads();   // all layer-1 reads of h1_prev done
    #pragma unroll
    for (int mt = 0; mt < 2; ++mt)
      #pragma unroll
      for (int q = 0; q < 4; ++q){
        int s = mt * 16 + quad * 4 + q;
        A1[s * 136 + 64 + jcol] = f2bf(hn[mt * 4 + q]);
      }
    // NOTE: no unconditional sync here — next step's layer-1 reads are
    // separated from these stores by the two syncs above. Head (t>=335)
    // syncs itself.

    // ================= head (only last 48 steps produce output) =========
    if (t >= 335){
      __syncthreads();   // h1 visible for head reads
      const int hs = tid >> 3, outc = (tid >> 2) & 1, part = tid & 3;
      const short8 hv0 = *(const short8*)&A1[hs * 136 + 64 + part * 16];
      const short8 hv1 = *(const short8*)&A1[hs * 136 + 64 + part * 16 + 8];
      float p = 0.f;
      #pragma unroll
      for (int jj = 0; jj < 8; ++jj){
        float a0 = fmaxf(bf2f((unsigned short)hv0[jj]), 0.f);
        float a1 = fmaxf(bf2f((unsigned short)hv1[jj]), 0.f);
        p += a0 * HW[outc * 64 + part * 16 + jj];
        p += a1 * HW[outc * 64 + part * 16 + 8 + jj];
      }
      p += __shfl_xor(p, 1);
      p += __shfl_xor(p, 2);
      if ((tid & 3) == 0){
        float val;
        if (outc == 0) val = p + hb0;
        else {
          float x = p + hb1;   // softplus, stable
          val = fmaxf(x, 0.f) + __logf(1.f + __expf(-fabsf(x)));
        }
        outp[(((size_t)b * 48 + (t - 335)) * 512 + (n0 + hs)) * 2 + outc] = val;
      }
    }
  }
}

extern "C" void kernel_launch(void* const* d_in, const int* in_sizes, int n_in,
                              void* d_out, int out_size, void* d_ws, size_t ws_size,
                              hipStream_t stream) {
  (void)in_sizes; (void)n_in; (void)out_size; (void)d_ws; (void)ws_size;
  deepar_kernel<<<dim3(512), dim3(256), 0, stream>>>(
      (const float*)d_in[0],  (const float*)d_in[1],
      (const float*)d_in[2],  (const float*)d_in[3],
      (const float*)d_in[4],  (const float*)d_in[5],
      (const float*)d_in[6],  (const float*)d_in[7],
      (const float*)d_in[8],  (const float*)d_in[9],
      (const float*)d_in[10], (const float*)d_in[11],
      (const float*)d_in[12], (const float*)d_in[13],
      (float*)d_out);
}

// Round 3
// 1336.825 us; speedup vs baseline: 1.0993x; 1.0390x over previous
//
#include <hip/hip_runtime.h>

// DeepAR forward: B=32, L_IN=336, L_OUT=48, N=512, COV=4, EMB=32, H=64
// T = 383 steps, BN = 16384 independent sequences.
// 32 sequences per 256-thread WG (512 WGs = 2 blocks/CU), persistent over T.
// Gate matmuls via mfma_f32_16x16x32_bf16.
// R2 analysis: VALU-issue-bound at ~70% busy with <2 waves/SIMD; register
// file (112 weight + 32 acc + 16 c + arch) caps occupancy. Fix: layer-1
// weight fragments live in LDS (65.5 KB/WG, 16 ds_read_b128/wave/step),
// layer-0 weights stay in regs. A0/A1 merged into one [h0|h1|in] buffer
// (stride 168) so h0 is stored once. Target: 3 waves/SIMD.

#define T_STEPS 383
#define AST 168   // A row stride in shorts: [h0 0..63 | h1 64..127 | in 128..132 | pad]

typedef __attribute__((ext_vector_type(8))) short short8;
typedef __attribute__((ext_vector_type(4))) float floatx4;

__device__ __forceinline__ unsigned short f2bf(float f){   // RNE (prologue)
  union { float f; unsigned u; } v; v.f = f;
  unsigned u = v.u + 0x7fffu + ((v.u >> 16) & 1u);
  return (unsigned short)(u >> 16);
}
__device__ __forceinline__ unsigned short f2bf_fast(float f){  // round-half-up, 2 instrs
  union { float f; unsigned u; } v; v.f = f;
  return (unsigned short)((v.u + 0x8000u) >> 16);
}
__device__ __forceinline__ float bf2f(unsigned short b){
  union { unsigned u; float f; } v; v.u = ((unsigned)b) << 16; return v.f;
}
__device__ __forceinline__ float fsig(float x){
  return __builtin_amdgcn_rcpf(1.f + __expf(-x));
}
__device__ __forceinline__ float ftanh(float x){
  return 1.f - 2.f * __builtin_amdgcn_rcpf(1.f + __expf(2.f * x));
}

__global__ __launch_bounds__(256, 2) void deepar_kernel(
    const float* __restrict__ hist, const float* __restrict__ fut,
    const float* __restrict__ embW, const float* __restrict__ embB,
    const float* __restrict__ Wih0, const float* __restrict__ Whh0,
    const float* __restrict__ bih0, const float* __restrict__ bhh0,
    const float* __restrict__ Wih1, const float* __restrict__ Whh1,
    const float* __restrict__ bih1, const float* __restrict__ bhh1,
    const float* __restrict__ headW, const float* __restrict__ headB,
    float* __restrict__ outp)
{
  const int tid  = threadIdx.x;
  const int lane = tid & 63;
  const int wv   = tid >> 6;        // wave -> gate-column sub-block
  const int l15  = lane & 15;
  const int quad = lane >> 4;       // 0..3
  const int koff = quad * 8;
  const int jcol = wv * 16 + l15;   // hidden-unit index this lane owns

  const int b  = blockIdx.x >> 4;            // batch
  const int n0 = (blockIdx.x & 15) * 32;     // first series index

  __shared__ __align__(16) unsigned short A[32 * AST];
  __shared__ __align__(16) unsigned short W1[256 * 128];  // layer-1 B-frags, frag-ordered
  __shared__ float HW[128];

  for (int i = tid; i < 32 * AST; i += 256) A[i] = 0;
  if (tid < 128) HW[tid] = headW[tid];
  const float hb0 = headB[0], hb1 = headB[1];

  // ---- layer-0 weight B-fragments in registers; layer-1 frags -> LDS ----
  // B-frag (16x16x32): lane holds B^T[n=lane&15][k = quad*8 + j], j=0..7
  short8 bf0[4][3];   // [gate][kf]: kf0,1 = Whh0 (k 0..63); kf2 = input cols (k 128..159)
  float  bi0[4], bi1[4];
  #pragma unroll
  for (int g = 0; g < 4; ++g){
    const int r = g * 64 + wv * 16 + l15;     // gate row 0..255
    float u = 0.f, bb = bih0[r] + bhh0[r];
    #pragma unroll
    for (int e = 0; e < 32; ++e){
      float wval = Wih0[r * 36 + e];
      u  += wval * embW[e];
      bb += wval * embB[e];
    }
    bi0[g] = bb;
    bi1[g] = bih1[r] + bhh1[r];
    #pragma unroll
    for (int kf = 0; kf < 2; ++kf)
      #pragma unroll
      for (int j = 0; j < 8; ++j)
        bf0[g][kf][j] = (short)f2bf(Whh0[r * 64 + kf * 32 + koff + j]);
    #pragma unroll
    for (int j = 0; j < 8; ++j){
      int kk = koff + j;          // local k within input frag; col = 128+kk
      float v = 0.f;
      if (kk == 0) v = u;                               // prev -> u[r]
      else if (kk >= 1 && kk <= 4) v = Wih0[r * 36 + 32 + (kk - 1)];
      bf0[g][2][j] = (short)f2bf(v);
    }
    #pragma unroll
    for (int kf = 0; kf < 4; ++kf){
      const float* src = (kf < 2) ? (Wih1 + r * 64 + kf * 32)
                                  : (Whh1 + r * 64 + (kf - 2) * 32);
      short8 w;
      #pragma unroll
      for (int j = 0; j < 8; ++j)
        w[j] = (short)f2bf(src[koff + j]);
      // frag-ordered: wave wv's (g,kf) frag at contiguous 64x16B, lane-linear
      *(short8*)&W1[(((wv * 16 + g * 4 + kf) * 64) + lane) * 8] = w;
    }
  }

  // ---- input staging (prev: 32 threads; cov: 128 threads) ----
  const bool isPrev = (tid < 32);
  const bool isCov  = (tid >= 64 && tid < 192);
  int ss = 0, cc = 0;
  if (isPrev){ ss = tid; cc = 0; }
  if (isCov) { ss = (tid - 64) >> 2; cc = 1 + ((tid - 64) & 3); }
  const int myN = n0 + ss;

  auto loadSlab = [&](int tt) -> float {
    if (isPrev){
      int l = tt; if (l > 383) l = 383;
      return (l < 336) ? hist[(((size_t)b * 336 + l) * 512 + myN) * 5]
                       : fut [(((size_t)b * 48 + (l - 336)) * 512 + myN) * 5];
    } else if (isCov){
      int l = tt + 1; if (l > 383) l = 383;
      return (l < 336) ? hist[(((size_t)b * 336 + l) * 512 + myN) * 5 + cc]
                       : fut [(((size_t)b * 48 + (l - 336)) * 512 + myN) * 5 + cc];
    }
    return 0.f;
  };

  float rIn = loadSlab(0);
  if (isPrev || isCov) A[ss * AST + 128 + cc] = f2bf(rIn);
  rIn = loadSlab(1);   // prefetch step 1

  float c0s[8], c1s[8];
  #pragma unroll
  for (int i = 0; i < 8; ++i){ c0s[i] = 0.f; c1s[i] = 0.f; }

  __syncthreads();

  for (int t = 0; t < T_STEPS; ++t){
    // ================= layer 0 (K-frags at col 0,32,128) =================
    floatx4 acc[4][2];
    #pragma unroll
    for (int g = 0; g < 4; ++g)
      #pragma unroll
      for (int mt = 0; mt < 2; ++mt){
        floatx4 binit = { bi0[g], bi0[g], bi0[g], bi0[g] };
        acc[g][mt] = binit;
      }
    const int c0off[3] = { 0, 32, 128 };
    #pragma unroll
    for (int mt = 0; mt < 2; ++mt){
      #pragma unroll
      for (int kf = 0; kf < 3; ++kf){
        short8 af = *(const short8*)&A[(mt * 16 + l15) * AST + c0off[kf] + koff];
        #pragma unroll
        for (int g = 0; g < 4; ++g)
          acc[g][mt] = __builtin_amdgcn_mfma_f32_16x16x32_bf16(af, bf0[g][kf], acc[g][mt], 0, 0, 0);
      }
    }
    float hn[8];
    #pragma unroll
    for (int mt = 0; mt < 2; ++mt)
      #pragma unroll
      for (int q = 0; q < 4; ++q){
        int idx = mt * 4 + q;
        float iv = acc[0][mt][q], fv = acc[1][mt][q];
        float gv = acc[2][mt][q], ov = acc[3][mt][q];
        float c = fsig(fv) * c0s[idx] + fsig(iv) * ftanh(gv);
        c0s[idx] = c;
        hn[idx] = fsig(ov) * ftanh(c);
      }
    __syncthreads();   // B1: all layer-0 reads of A done
    #pragma unroll
    for (int mt = 0; mt < 2; ++mt)
      #pragma unroll
      for (int q = 0; q < 4; ++q){
        int s = mt * 16 + quad * 4 + q;
        A[s * AST + jcol] = f2bf_fast(hn[mt * 4 + q]);   // h0(t), single store
      }
    if (isPrev || isCov) A[ss * AST + 128 + cc] = f2bf_fast(rIn);  // inputs t+1
    rIn = loadSlab(t + 2);                                          // prefetch t+2
    __syncthreads();   // B2: h0 + inputs visible

    // ================= layer 1 (K = h0|h1, cols 0..127; W from LDS) ======
    #pragma unroll
    for (int g = 0; g < 4; ++g)
      #pragma unroll
      for (int mt = 0; mt < 2; ++mt){
        floatx4 binit = { bi1[g], bi1[g], bi1[g], bi1[g] };
        acc[g][mt] = binit;
      }
    #pragma unroll
    for (int kf = 0; kf < 4; ++kf){
      short8 wfr[4];
      #pragma unroll
      for (int g = 0; g < 4; ++g)
        wfr[g] = *(const short8*)&W1[(((wv * 16 + g * 4 + kf) * 64) + lane) * 8];
      #pragma unroll
      for (int mt = 0; mt < 2; ++mt){
        short8 af = *(const short8*)&A[(mt * 16 + l15) * AST + kf * 32 + koff];
        #pragma unroll
        for (int g = 0; g < 4; ++g)
          acc[g][mt] = __builtin_amdgcn_mfma_f32_16x16x32_bf16(af, wfr[g], acc[g][mt], 0, 0, 0);
      }
    }
    #pragma unroll
    for (int mt = 0; mt < 2; ++mt)
      #pragma unroll
      for (int q = 0; q < 4; ++q){
        int idx = mt * 4 + q;
        float iv = acc[0][mt][q], fv = acc[1][mt][q];
        float gv = acc[2][mt][q], ov = acc[3][mt][q];
        float c = fsig(fv) * c1s[idx] + fsig(iv) * ftanh(gv);
        c1s[idx] = c;
        hn[idx] = fsig(ov) * ftanh(c);
      }
    __syncthreads();   // B3: all layer-1 reads of h1(t-1) done
    #pragma unroll
    for (int mt = 0; mt < 2; ++mt)
      #pragma unroll
      for (int q = 0; q < 4; ++q){
        int s = mt * 16 + quad * 4 + q;
        A[s * AST + 64 + jcol] = f2bf_fast(hn[mt * 4 + q]);   // h1(t)
      }
    // next step's layer-0 reads cols 0..63/128..159 only — no barrier needed
    // until B1; h1 readers (next layer-1) are behind B1+B2.

    // ================= head (only last 48 steps produce output) =========
    if (t >= 335){
      __syncthreads();   // h1 visible for head reads
      const int hs = tid >> 3, outc = (tid >> 2) & 1, part = tid & 3;
      const short8 hv0 = *(const short8*)&A[hs * AST + 64 + part * 16];
      const short8 hv1 = *(const short8*)&A[hs * AST + 64 + part * 16 + 8];
      float p = 0.f;
      #pragma unroll
      for (int jj = 0; jj < 8; ++jj){
        float a0 = fmaxf(bf2f((unsigned short)hv0[jj]), 0.f);
        float a1 = fmaxf(bf2f((unsigned short)hv1[jj]), 0.f);
        p += a0 * HW[outc * 64 + part * 16 + jj];
        p += a1 * HW[outc * 64 + part * 16 + 8 + jj];
      }
      p += __shfl_xor(p, 1);
      p += __shfl_xor(p, 2);
      if ((tid & 3) == 0){
        float val;
        if (outc == 0) val = p + hb0;
        else {
          float x = p + hb1;   // softplus, stable
          val = fmaxf(x, 0.f) + __logf(1.f + __expf(-fabsf(x)));
        }
        outp[(((size_t)b * 48 + (t - 335)) * 512 + (n0 + hs)) * 2 + outc] = val;
      }
    }
  }
}

extern "C" void kernel_launch(void* const* d_in, const int* in_sizes, int n_in,
                              void* d_out, int out_size, void* d_ws, size_t ws_size,
                              hipStream_t stream) {
  (void)in_sizes; (void)n_in; (void)out_size; (void)d_ws; (void)ws_size;
  deepar_kernel<<<dim3(512), dim3(256), 0, stream>>>(
      (const float*)d_in[0],  (const float*)d_in[1],
      (const float*)d_in[2],  (const float*)d_in[3],
      (const float*)d_in[4],  (const float*)d_in[5],
      (const float*)d_in[6],  (const float*)d_in[7],
      (const float*)d_in[8],  (const float*)d_in[9],
      (const float*)d_in[10], (const float*)d_in[11],
      (const float*)d_in[12], (const float*)d_in[13],
      (float*)d_out);
}